// Round 1
// baseline (3152.310 us; speedup 1.0000x reference)
//
#include <hip/hip_runtime.h>

// ---------------- helpers ----------------

__device__ __forceinline__ unsigned encf(float f) {
    unsigned u = __float_as_uint(f);
    return (u & 0x80000000u) ? ~u : (u | 0x80000000u);
}
__device__ __forceinline__ float decf(unsigned e) {
    unsigned u = (e & 0x80000000u) ? (e & 0x7FFFFFFFu) : ~e;
    return __uint_as_float(u);
}

// ---------------- node MLP: feature attention + projection ----------------
// fw = sigmoid(relu(x@faW1+b1)@faW2+b2); h = (x*fw)@projW + projb
// one wave per node; lane j owns feature j of each 64-wide stage.
__global__ void k_mlp(const float* __restrict__ x,
                      const float* __restrict__ faW1, const float* __restrict__ fab1,
                      const float* __restrict__ faW2, const float* __restrict__ fab2,
                      const float* __restrict__ projW, const float* __restrict__ projb,
                      float* __restrict__ hbuf, int N) {
    int wid  = (blockIdx.x * blockDim.x + threadIdx.x) >> 6;
    int lane = threadIdx.x & 63;
    if (wid >= N) return;
    const size_t base = (size_t)wid * 128;
    float x0 = x[base + lane];
    float x1 = x[base + 64 + lane];

    // t = relu(x @ faW1 + b1)   [64]
    float t = fab1[lane];
#pragma unroll
    for (int i = 0; i < 64; ++i) {
        t = fmaf(__shfl(x0, i, 64), faW1[i * 64 + lane], t);
        t = fmaf(__shfl(x1, i, 64), faW1[(64 + i) * 64 + lane], t);
    }
    t = fmaxf(t, 0.f);

    // fw = sigmoid(t @ faW2 + b2)  [128]; lane holds k=lane and k=64+lane
    float f0 = fab2[lane], f1 = fab2[64 + lane];
#pragma unroll
    for (int j = 0; j < 64; ++j) {
        float tj = __shfl(t, j, 64);
        f0 = fmaf(tj, faW2[j * 128 + lane], f0);
        f1 = fmaf(tj, faW2[j * 128 + 64 + lane], f1);
    }
    // xm = x * sigmoid(fw)
    f0 = x0 / (1.f + expf(-f0));
    f1 = x1 / (1.f + expf(-f1));

    // h = xm @ projW + projb  [64]
    float h = projb[lane];
#pragma unroll
    for (int i = 0; i < 64; ++i) {
        h = fmaf(__shfl(f0, i, 64), projW[i * 64 + lane], h);
        h = fmaf(__shfl(f1, i, 64), projW[(64 + i) * 64 + lane], h);
    }
    hbuf[(size_t)wid * 64 + lane] = h;
}

// ---------------- GAT: z = h@W, es = z.asrc, ed = z.adst ----------------
__global__ void k_z(const float* __restrict__ hbuf, const float* __restrict__ W,
                    const float* __restrict__ asrc, const float* __restrict__ adst,
                    float* __restrict__ zbuf, float* __restrict__ es, float* __restrict__ ed,
                    int N) {
    int wid  = (blockIdx.x * blockDim.x + threadIdx.x) >> 6;
    int lane = threadIdx.x & 63;
    if (wid >= N) return;
    float h = hbuf[(size_t)wid * 64 + lane];
    float z = 0.f;
#pragma unroll
    for (int i = 0; i < 64; ++i)
        z = fmaf(__shfl(h, i, 64), W[i * 64 + lane], z);
    zbuf[(size_t)wid * 64 + lane] = z;
    float vs = z * asrc[lane];
    float vd = z * adst[lane];
#pragma unroll
    for (int off = 32; off; off >>= 1) {
        vs += __shfl_xor(vs, off, 64);
        vd += __shfl_xor(vd, off, 64);
    }
    if (lane == 0) { es[wid] = vs; ed[wid] = vd; }
}

// ---------------- edge pass 1: segment max ----------------
__global__ void k_edge_max(const int* __restrict__ ei, int E, int Etot,
                           const float* __restrict__ es, const float* __restrict__ ed,
                           unsigned* __restrict__ maxenc) {
    int i = blockIdx.x * blockDim.x + threadIdx.x;
    if (i >= Etot) return;
    int s, d;
    if (i < E) { s = ei[i]; d = ei[E + i]; } else { s = d = i - E; }
    float v = es[s] + ed[d];
    v = v >= 0.f ? v : 0.2f * v;
    atomicMax(&maxenc[d], encf(v));
}

// ---------------- edge pass 2: denom = segment sum of exp(e - m) ----------------
__global__ void k_edge_denom(const int* __restrict__ ei, int E, int Etot,
                             const float* __restrict__ es, const float* __restrict__ ed,
                             const unsigned* __restrict__ maxenc, float* __restrict__ denom) {
    int i = blockIdx.x * blockDim.x + threadIdx.x;
    if (i >= Etot) return;
    int s, d;
    if (i < E) { s = ei[i]; d = ei[E + i]; } else { s = d = i - E; }
    float v = es[s] + ed[d];
    v = v >= 0.f ? v : 0.2f * v;
    atomicAdd(&denom[d], expf(v - decf(maxenc[d])));
}

// ---------------- edge pass 3: acc[dst] += z[src] * alpha ----------------
__global__ void k_scatter(const int* __restrict__ ei, int E, int Etot,
                          const float* __restrict__ es, const float* __restrict__ ed,
                          const unsigned* __restrict__ maxenc, const float* __restrict__ denom,
                          const float* __restrict__ zbuf, float* __restrict__ acc) {
    int idx = blockIdx.x * blockDim.x + threadIdx.x;
    int total = Etot << 6;
    if (idx >= total) return;
    int e = idx >> 6, j = idx & 63;
    int s, d;
    if (e < E) { s = ei[e]; d = ei[E + e]; } else { s = d = e - E; }
    float v = es[s] + ed[d];
    v = v >= 0.f ? v : 0.2f * v;
    float alpha = expf(v - decf(maxenc[d])) / denom[d];
    atomicAdd(&acc[(size_t)d * 64 + j], zbuf[(size_t)s * 64 + j] * alpha);
}

// ---------------- bias + BN(eval) + ReLU ----------------
__global__ void k_bnrelu(const float* __restrict__ acc, const float* __restrict__ b,
                         const float* __restrict__ g, const float* __restrict__ bta,
                         const float* __restrict__ mean, const float* __restrict__ var,
                         float* __restrict__ hbuf, int N) {
    int idx = blockIdx.x * blockDim.x + threadIdx.x;
    if (idx >= N * 64) return;
    int j = idx & 63;
    float scale = g[j] * rsqrtf(var[j] + 1e-5f);
    float v = (acc[idx] + b[j] - mean[j]) * scale + bta[j];
    hbuf[idx] = fmaxf(v, 0.f);
}

// ---------------- structural: degree ----------------
__global__ void k_deg(const int* __restrict__ ei, int E, float* __restrict__ deg) {
    int e = blockIdx.x * blockDim.x + threadIdx.x;
    if (e < E) atomicAdd(&deg[ei[e]], 1.f);
}
__global__ void k_inflsum(const int* __restrict__ ei, int E,
                          const float* __restrict__ deg, float* __restrict__ inflsum) {
    int e = blockIdx.x * blockDim.x + threadIdx.x;
    if (e < E) atomicAdd(&inflsum[ei[e]], deg[ei[E + e]]);
}
__global__ void k_infl(const float* __restrict__ deg, const float* __restrict__ inflsum,
                       float* __restrict__ inflv, unsigned* __restrict__ scal, int N) {
    int idx = blockIdx.x * blockDim.x + threadIdx.x;
    float d = 0.f, iv = 0.f;
    if (idx < N) {
        d = deg[idx];
        iv = d > 0.f ? inflsum[idx] / d : 0.f;
        inflv[idx] = iv;
    }
    float dm = d, im = iv;
#pragma unroll
    for (int off = 32; off; off >>= 1) {
        dm = fmaxf(dm, __shfl_xor(dm, off, 64));
        im = fmaxf(im, __shfl_xor(im, off, 64));
    }
    if ((threadIdx.x & 63) == 0) {
        atomicMax(scal + 0, __float_as_uint(dm));   // deg >= 0: bits are order-preserving
        atomicMax(scal + 1, __float_as_uint(im));
    }
}

// ---------------- structural MLP + concat + output MLP ----------------
__global__ void k_final(const float* __restrict__ hbuf, const float* __restrict__ deg,
                        const float* __restrict__ inflv, const unsigned* __restrict__ scal,
                        const float* __restrict__ seW1, const float* __restrict__ seb1,
                        const float* __restrict__ seW2, const float* __restrict__ seb2,
                        const float* __restrict__ oW1, const float* __restrict__ ob1,
                        const float* __restrict__ oW2, const float* __restrict__ ob2,
                        const float* __restrict__ oW3, const float* __restrict__ ob3,
                        float* __restrict__ out, int N) {
    int wid  = (blockIdx.x * blockDim.x + threadIdx.x) >> 6;
    int lane = threadIdx.x & 63;
    if (wid >= N) return;
    int lk = lane & 31;

    float degmax  = fmaxf(__uint_as_float(scal[0]), 1.0f);
    float inflmax = fmaxf(__uint_as_float(scal[1]), 1e-12f);
    float nd = deg[wid] / degmax;
    float fl = inflv[wid] / inflmax;
    float h = hbuf[(size_t)wid * 64 + lane];

    // hidden = relu(sf @ seW1 + seb1), sf = [nd, 0, fl]; seW1 is [3][32]
    float hid = fmaxf(nd * seW1[lk] + fl * seW1[64 + lk] + seb1[lk], 0.f);

    // se = hidden @ seW2 + seb2   [64]
    float se = seb2[lane];
#pragma unroll
    for (int k = 0; k < 32; ++k)
        se = fmaf(__shfl(hid, k, 64), seW2[k * 64 + lane], se);

    // o1 = relu([h, se] @ oW1 + ob1)  [64]
    float o1 = ob1[lane];
#pragma unroll
    for (int i = 0; i < 64; ++i) {
        o1 = fmaf(__shfl(h, i, 64),  oW1[i * 64 + lane], o1);
        o1 = fmaf(__shfl(se, i, 64), oW1[(64 + i) * 64 + lane], o1);
    }
    o1 = fmaxf(o1, 0.f);

    // o2 = relu(o1 @ oW2 + ob2)  [32] (lanes 32..63 compute duplicates)
    float o2 = ob2[lk];
#pragma unroll
    for (int j = 0; j < 64; ++j)
        o2 = fmaf(__shfl(o1, j, 64), oW2[j * 32 + lk], o2);
    o2 = fmaxf(o2, 0.f);

    // out = sigmoid(o2 @ oW3 + ob3)
    float c = (lane < 32) ? o2 * oW3[lk] : 0.f;
#pragma unroll
    for (int off = 32; off; off >>= 1) c += __shfl_xor(c, off, 64);
    if (lane == 0) out[wid] = 1.f / (1.f + expf(-(c + ob3[0])));
}

// ---------------- launch ----------------
extern "C" void kernel_launch(void* const* d_in, const int* in_sizes, int n_in,
                              void* d_out, int out_size, void* d_ws, size_t ws_size,
                              hipStream_t stream) {
    const float* x     = (const float*)d_in[0];
    const int*   ei    = (const int*)d_in[1];
    const float* faW1  = (const float*)d_in[2];
    const float* fab1  = (const float*)d_in[3];
    const float* faW2  = (const float*)d_in[4];
    const float* fab2  = (const float*)d_in[5];
    const float* projW = (const float*)d_in[6];
    const float* projb = (const float*)d_in[7];
    const float* gatW  = (const float*)d_in[8];
    const float* gatAs = (const float*)d_in[9];
    const float* gatAd = (const float*)d_in[10];
    const float* gatB  = (const float*)d_in[11];
    const float* bnG   = (const float*)d_in[12];
    const float* bnB   = (const float*)d_in[13];
    const float* bnM   = (const float*)d_in[14];
    const float* bnV   = (const float*)d_in[15];
    const float* seW1  = (const float*)d_in[16];
    const float* seb1  = (const float*)d_in[17];
    const float* seW2  = (const float*)d_in[18];
    const float* seb2  = (const float*)d_in[19];
    const float* oW1   = (const float*)d_in[20];
    const float* ob1   = (const float*)d_in[21];
    const float* oW2   = (const float*)d_in[22];
    const float* ob2   = (const float*)d_in[23];
    const float* oW3   = (const float*)d_in[24];
    const float* ob3   = (const float*)d_in[25];
    float* out = (float*)d_out;

    const int N    = in_sizes[0] / 128;
    const int E    = in_sizes[1] / 2;
    const int Etot = E + N;

    float* ws      = (float*)d_ws;
    float* hbuf    = ws;
    float* zbuf    = hbuf + (size_t)N * 64;
    float* accbuf  = zbuf + (size_t)N * 64;
    float* es      = accbuf + (size_t)N * 64;
    float* ed      = es + N;
    unsigned* maxenc = (unsigned*)(ed + N);
    float* denom   = (float*)(maxenc + N);
    float* deg     = denom + N;
    float* inflsum = deg + N;
    float* inflv   = inflsum + N;
    unsigned* scal = (unsigned*)(inflv + N);

    dim3 blk(256);
    int blkNodeWave = (N * 64 + 255) / 256;
    int blkE        = (E + 255) / 256;
    int blkEtot     = (Etot + 255) / 256;
    int blkNF       = (N * 64 + 255) / 256;
    int blkN        = (N + 255) / 256;
    int blkScatter  = (int)(((long long)Etot * 64 + 255) / 256);

    // zero deg, inflsum, inflv, scal (contiguous)
    hipMemsetAsync(deg, 0, ((size_t)3 * N + 8) * sizeof(float), stream);

    k_mlp<<<blkNodeWave, blk, 0, stream>>>(x, faW1, fab1, faW2, fab2, projW, projb, hbuf, N);
    k_deg<<<blkE, blk, 0, stream>>>(ei, E, deg);
    k_inflsum<<<blkE, blk, 0, stream>>>(ei, E, deg, inflsum);
    k_infl<<<blkN, blk, 0, stream>>>(deg, inflsum, inflv, scal, N);

    for (int l = 0; l < 3; ++l) {
        hipMemsetAsync(maxenc, 0, (size_t)2 * N * sizeof(unsigned), stream);
        hipMemsetAsync(accbuf, 0, (size_t)N * 64 * sizeof(float), stream);
        k_z<<<blkNodeWave, blk, 0, stream>>>(hbuf, gatW + l * 4096, gatAs + l * 64, gatAd + l * 64,
                                             zbuf, es, ed, N);
        k_edge_max<<<blkEtot, blk, 0, stream>>>(ei, E, Etot, es, ed, maxenc);
        k_edge_denom<<<blkEtot, blk, 0, stream>>>(ei, E, Etot, es, ed, maxenc, denom);
        k_scatter<<<blkScatter, blk, 0, stream>>>(ei, E, Etot, es, ed, maxenc, denom, zbuf, accbuf);
        k_bnrelu<<<blkNF, blk, 0, stream>>>(accbuf, gatB + l * 64, bnG + l * 64, bnB + l * 64,
                                            bnM + l * 64, bnV + l * 64, hbuf, N);
    }

    k_final<<<blkNodeWave, blk, 0, stream>>>(hbuf, deg, inflv, scal, seW1, seb1, seW2, seb2,
                                             oW1, ob1, oW2, ob2, oW3, ob3, out, N);
}